// Round 1
// baseline (647.278 us; speedup 1.0000x reference)
//
#include <hip/hip_runtime.h>

#define EPS 1e-5f
#define ONE_M_EPS (1.0f - 1e-5f)
#define NROW 2048
#define FF 20
#define DH 64

__device__ __forceinline__ float wred(float v) {
#pragma unroll
  for (int m = 32; m >= 1; m >>= 1) v += __shfl_xor(v, m, 64);
  return v;
}

__device__ __forceinline__ float ftanh(float x) {
  float ax = fabsf(x);
  float e = __expf(-2.f * ax);
  float t = (1.f - e) / (1.f + e);
  return copysignf(t, x);
}

// x in [0, 1-EPS]
__device__ __forceinline__ float fatanh(float x) {
  return 0.5f * __logf((1.f + x) / (1.f - x));
}

// x >= 1
__device__ __forceinline__ float facosh(float x) {
  return __logf(x + sqrtf(fmaxf(x * x - 1.f, 0.f)));
}

__device__ __forceinline__ float clampn(float x) {
  return fminf(fmaxf(x, EPS), ONE_M_EPS);
}

// f = exp0(concat(emb0[x0], emb1[x1]) @ win + bin)
__global__ __launch_bounds__(64) void feat_kernel(
    const int* __restrict__ x, const float* __restrict__ emb0,
    const float* __restrict__ emb1, const float* __restrict__ win,
    const float* __restrict__ binp, float* __restrict__ fout) {
  const int n = blockIdx.x;
  const int l = threadIdx.x;
  __shared__ float u[DH];
  int x0 = x[n * 2 + 0];
  int x1 = x[n * 2 + 1];
  u[l] = (l < 32) ? emb0[x0 * 32 + l] : emb1[x1 * 32 + (l - 32)];
  __syncthreads();
  float acc = binp[l];
#pragma unroll
  for (int k = 0; k < DH; ++k) acc = fmaf(u[k], win[k * DH + l], acc);
  float a2 = wred(acc * acc);
  float nn = sqrtf(a2 + 1e-15f);
  fout[n * DH + l] = ftanh(nn) / fmaxf(nn, EPS) * acc;
}

// e = mob_add(mob_scalar(fv, r), exp0(sum_i log0(mob_scalar(Ns[i], att_i))))
__device__ __forceinline__ float aggregate_fn(const float (*Ns)[DH],
                                              const float* N2, const float* NN,
                                              const float* NA, float fv,
                                              float f2, float fnc, float fA,
                                              float r, int l) {
  float dist[FF];
#pragma unroll
  for (int i = 0; i < FF; ++i) {
    float dif = fv - Ns[i][l];
    float d2 = wred(dif * dif);
    float den = fmaxf((1.f - f2) * (1.f - N2[i]), EPS);
    float arg = fmaxf(1.f + 2.f * d2 / den, 1.f + 1e-7f);
    dist[i] = facosh(arg);
  }
  float mn = dist[0];
#pragma unroll
  for (int i = 1; i < FF; ++i) mn = fminf(mn, dist[i]);
  float s = 0.f;
  float g[FF];
#pragma unroll
  for (int i = 0; i < FF; ++i) {
    g[i] = __expf(mn - dist[i]);
    s += g[i];
  }
  float inv = 1.f / s;
  float acc = 0.f;
#pragma unroll
  for (int i = 0; i < FF; ++i) {
    float gg = g[i] * inv;
    float t = ftanh(gg * NA[i]);
    float yf = t / NN[i];
    float ny = sqrtf(yf * yf * N2[i] + 1e-15f);
    float nc = clampn(ny);
    float k = fatanh(nc) / nc * yf;
    acc = fmaf(k, Ns[i][l], acc);
  }
  float a2 = wred(acc * acc);
  float nn = sqrtf(a2 + 1e-15f);
  float nTE = ftanh(nn) / fmaxf(nn, EPS) * acc;
  float fs = ftanh(r * fA) / fnc;
  float xv = fs * fv;
  float x2 = wred(xv * xv);
  float y2 = wred(nTE * nTE);
  float xy = wred(xv * nTE);
  float num = (1.f + 2.f * xy + y2) * xv + (1.f - x2) * nTE;
  float dden = fmaxf(1.f + 2.f * xy + x2 * y2, EPS);
  return num / dden;
}

__global__ __launch_bounds__(64) void mode_kernel(
    const float* __restrict__ f, const int* __restrict__ Didx,
    const int* __restrict__ Qidx, const float* __restrict__ q1p,
    const float* __restrict__ qp, const float* __restrict__ qqp,
    const float* __restrict__ aw1, const float* __restrict__ ab1,
    const float* __restrict__ aw2, const float* __restrict__ wout,
    const float* __restrict__ bout, float* __restrict__ out) {
  const int n = blockIdx.x;
  const int l = threadIdx.x;
  __shared__ float Qs[FF][DH], Hs[FF][DH];
  __shared__ float Q2[FF], QN[FF], QA[FF];
  __shared__ float S2[FF], SN[FF], SA[FF];
  __shared__ float zb[2][DH];
  __shared__ float ub[DH];

  float fv = f[n * DH + l];
  for (int i = 0; i < FF; ++i) {
    Hs[i][l] = f[Didx[n * FF + i] * DH + l];  // D tile (later overwritten by h_neigh)
    Qs[i][l] = f[Qidx[n * FF + i] * DH + l];
  }
  __syncthreads();

  // per-neighbor precompute: sqnorm, clipped norm, atanh(clipped norm)
  for (int j = 0; j < FF; ++j) {
    float qv = Qs[j][l];
    float s2 = wred(qv * qv);
    float dv = Hs[j][l];
    float t2 = wred(dv * dv);
    if (l == 0) {
      Q2[j] = s2;
      float ncq = clampn(sqrtf(s2 + 1e-15f));
      QN[j] = ncq;
      QA[j] = fatanh(ncq);
      S2[j] = t2;
      float ncd = clampn(sqrtf(t2 + 1e-15f));
      SN[j] = ncd;
      SA[j] = fatanh(ncd);
    }
  }
  __syncthreads();

  float f2 = wred(fv * fv);
  float fnc = clampn(sqrtf(f2 + 1e-15f));
  float fA = fatanh(fnc);
  float q1 = q1p[0], qsc = qp[0], qqsc = qqp[0];

  // ---- co-attention: for each D slot i, attend over Q neighbors ----
  for (int i = 0; i < FF; ++i) {
    float dl = Hs[i][l];
    float D2i = S2[i];
    float dist[FF];
#pragma unroll
    for (int j = 0; j < FF; ++j) {
      float dif = dl - Qs[j][l];
      float d2 = wred(dif * dif);
      float den = fmaxf((1.f - D2i) * (1.f - Q2[j]), EPS);
      float arg = fmaxf(1.f + 2.f * d2 / den, 1.f + 1e-7f);
      dist[j] = facosh(arg);
    }
    float mn = dist[0];
#pragma unroll
    for (int j = 1; j < FF; ++j) mn = fminf(mn, dist[j]);
    float ssum = 0.f;
    float g[FF];
#pragma unroll
    for (int j = 0; j < FF; ++j) {
      g[j] = __expf(mn - dist[j]);
      ssum += g[j];
    }
    float inv = 1.f / ssum;
    float acc = 0.f;
#pragma unroll
    for (int j = 0; j < FF; ++j) {
      float gg = g[j] * inv;
      float t = ftanh(gg * QA[j]);   // tanh(G * artanh(|Q|))
      float yf = t / QN[j];          // mob_scalar factor
      float ny = sqrtf(yf * yf * Q2[j] + 1e-15f);
      float nc = clampn(ny);
      float k = fatanh(nc) / nc * yf;  // log0 factor * mob_scalar factor
      acc = fmaf(k, Qs[j][l], acc);
    }
    // nh = exp0(acc)
    float a2 = wred(acc * acc);
    float nn = sqrtf(a2 + 1e-15f);
    float nh = ftanh(nn) / fmaxf(nn, EPS) * acc;
    // mob_scalar(D_i, q1)
    float fDc = ftanh(q1 * SA[i]) / SN[i];
    float xv = fDc * dl;
    // mob_add(xv, nh)
    float x2 = wred(xv * xv);
    float y2 = wred(nh * nh);
    float xy = wred(xv * nh);
    float num = (1.f + 2.f * xy + y2) * xv + (1.f - x2) * nh;
    float dden = fmaxf(1.f + 2.f * xy + x2 * y2, EPS);
    float hv = num / dden;
    float h2 = wred(hv * hv);
    __syncthreads();
    Hs[i][l] = hv;  // overwrite D slot with h_neigh
    if (l == 0) {
      S2[i] = h2;
      float nc = clampn(sqrtf(h2 + 1e-15f));
      SN[i] = nc;
      SA[i] = fatanh(nc);
    }
    __syncthreads();
  }

  float e1 = aggregate_fn(Hs, S2, SN, SA, fv, f2, fnc, fA, qsc, l);
  float e2 = aggregate_fn(Qs, Q2, QN, QA, fv, f2, fnc, fA, qqsc, l);

  // z = stack(log0(e1), log0(e2))
  float e1s = wred(e1 * e1);
  float n1 = clampn(sqrtf(e1s + 1e-15f));
  float z0 = fatanh(n1) / n1 * e1;
  float e2s = wred(e2 * e2);
  float n2 = clampn(sqrtf(e2s + 1e-15f));
  float z1 = fatanh(n2) / n2 * e2;
  zb[0][l] = z0;
  zb[1][l] = z1;
  __syncthreads();

  // beta = softmax(tanh(z @ aw1 + ab1) @ aw2, axis=pair); lane = pair*32 + col
  int p_ = l >> 5, c_ = l & 31;
  float mm = ab1[c_];
#pragma unroll
  for (int k = 0; k < DH; ++k) mm = fmaf(zb[p_][k], aw1[k * 32 + c_], mm);
  float tt = ftanh(mm);
  float sr = tt * aw2[c_];
#pragma unroll
  for (int m = 16; m >= 1; m >>= 1) sr += __shfl_xor(sr, m, 64);
  float s0 = __shfl(sr, 0, 64);
  float s1 = __shfl(sr, 32, 64);
  float bm = fmaxf(s0, s1);
  float b0 = __expf(s0 - bm), b1 = __expf(s1 - bm);
  float bi = 1.f / (b0 + b1);
  b0 *= bi;
  b1 *= bi;

  // rst = exp0(b0*z0 + b1*z1)
  float rv = fmaf(b0, z0, b1 * z1);
  float r2 = wred(rv * rv);
  float rn = sqrtf(r2 + 1e-15f);
  float rst = ftanh(rn) / fmaxf(rn, EPS) * rv;
  // u = log0(rst)
  float rr = wred(rst * rst);
  float rc = clampn(sqrtf(rr + 1e-15f));
  float uu = fatanh(rc) / rc * rst;
  ub[l] = uu;
  __syncthreads();
  // out = exp0(u @ wout + bout)
  float oo = bout[l];
#pragma unroll
  for (int k = 0; k < DH; ++k) oo = fmaf(ub[k], wout[k * DH + l], oo);
  float o2 = wred(oo * oo);
  float on = sqrtf(o2 + 1e-15f);
  out[n * DH + l] = ftanh(on) / fmaxf(on, EPS) * oo;
}

extern "C" void kernel_launch(void* const* d_in, const int* in_sizes, int n_in,
                              void* d_out, int out_size, void* d_ws,
                              size_t ws_size, hipStream_t stream) {
  const int* x = (const int*)d_in[0];
  const int* idx_sim = (const int*)d_in[1];
  const int* idx_cor = (const int*)d_in[2];
  // per-mode params: 0 emb0, 1 emb1, 2 win, 3 bin, 4 q, 5 qq, 6 q1,
  //                  7 aw1, 8 ab1, 9 aw2, 10 wout, 11 bout
  const float* p[2][12];
  for (int m = 0; m < 2; ++m)
    for (int k = 0; k < 12; ++k) p[m][k] = (const float*)d_in[3 + m * 12 + k];

  float* fsim = (float*)d_ws;
  float* fcor = fsim + NROW * DH;
  float* out = (float*)d_out;

  feat_kernel<<<NROW, 64, 0, stream>>>(x, p[0][0], p[0][1], p[0][2], p[0][3], fsim);
  feat_kernel<<<NROW, 64, 0, stream>>>(x, p[1][0], p[1][1], p[1][2], p[1][3], fcor);

  // mode 'sim': D = f[idx_cor], Q = f[idx_sim]
  mode_kernel<<<NROW, 64, 0, stream>>>(fsim, idx_cor, idx_sim, p[0][6], p[0][4],
                                       p[0][5], p[0][7], p[0][8], p[0][9],
                                       p[0][10], p[0][11], out);
  // mode 'cor': D = f[idx_sim], Q = f[idx_cor]
  mode_kernel<<<NROW, 64, 0, stream>>>(fcor, idx_sim, idx_cor, p[1][6], p[1][4],
                                       p[1][5], p[1][7], p[1][8], p[1][9],
                                       p[1][10], p[1][11], out + NROW * DH);
}

// Round 2
// 511.588 us; speedup vs baseline: 1.2652x; 1.2652x over previous
//
#include <hip/hip_runtime.h>

#define EPS 1e-5f
#define ONE_M_EPS (1.0f - 1e-5f)
#define NROW 2048
#define FF 20
#define DH 64

__device__ __forceinline__ float wred(float v) {
#pragma unroll
  for (int m = 32; m >= 1; m >>= 1) v += __shfl_xor(v, m, 64);
  return v;
}

__device__ __forceinline__ float ftanh(float x) {
  float ax = fabsf(x);
  float e = __expf(-2.f * ax);
  float t = (1.f - e) / (1.f + e);
  return copysignf(t, x);
}

// x in [0, 1-EPS]
__device__ __forceinline__ float fatanh(float x) {
  return 0.5f * __logf((1.f + x) / (1.f - x));
}

// x >= 1
__device__ __forceinline__ float facosh(float x) {
  return __logf(x + sqrtf(fmaxf(x * x - 1.f, 0.f)));
}

__device__ __forceinline__ float clampn(float x) {
  return fminf(fmaxf(x, EPS), ONE_M_EPS);
}

struct FeatParams {
  const float *emb0, *emb1, *win, *bin;
  float* fout;
};

struct ModeParams {
  const float* f;
  const int *Didx, *Qidx;
  const float *q1p, *qp, *qqp, *aw1, *ab1, *aw2, *wout, *bout;
  float* out;
};

// f = exp0(concat(emb0[x0], emb1[x1]) @ win + bin); both modes in one grid
__global__ __launch_bounds__(64) void feat_kernel(const int* __restrict__ x,
                                                  FeatParams ps, FeatParams pc) {
  const int bid = blockIdx.x;
  const int mode = bid >= NROW;
  const FeatParams P = mode ? pc : ps;
  const int n = bid - mode * NROW;
  const int l = threadIdx.x;
  __shared__ float u[DH];
  int x0 = x[n * 2 + 0];
  int x1 = x[n * 2 + 1];
  u[l] = (l < 32) ? P.emb0[x0 * 32 + l] : P.emb1[x1 * 32 + (l - 32)];
  __syncthreads();
  float acc = P.bin[l];
#pragma unroll
  for (int k = 0; k < DH; ++k) acc = fmaf(u[k], P.win[k * DH + l], acc);
  float a2 = wred(acc * acc);
  float nn = sqrtf(a2 + 1e-15f);
  P.fout[n * DH + l] = ftanh(nn) / fmaxf(nn, EPS) * acc;
}

// e = mob_add(mob_scalar(fv, r), exp0(sum_i log0(mob_scalar(Ns[i], att_i))))
__device__ __forceinline__ float aggregate_fn(const float (*Ns)[DH],
                                              const float* N2, const float* NN,
                                              const float* NA, float fv,
                                              float f2, float fnc, float fA,
                                              float r, int l) {
  float g[FF];
  float s = 0.f;
#pragma unroll
  for (int i = 0; i < FF; ++i) {
    float dif = fv - Ns[i][l];
    float d2 = wred(dif * dif);
    float den = fmaxf((1.f - f2) * (1.f - N2[i]), EPS);
    float arg = fmaxf(1.f + 2.f * d2 / den, 1.f + 1e-7f);
    g[i] = __expf(-facosh(arg));
    s += g[i];
  }
  float inv = 1.f / s;
  float acc = 0.f;
#pragma unroll
  for (int i = 0; i < FF; ++i) {
    float gg = g[i] * inv;
    float t = ftanh(gg * NA[i]);
    float yf = t / NN[i];
    float ny = sqrtf(yf * yf * N2[i] + 1e-15f);
    float nc = clampn(ny);
    float k = fatanh(nc) / nc * yf;
    acc = fmaf(k, Ns[i][l], acc);
  }
  float a2 = wred(acc * acc);
  float nn = sqrtf(a2 + 1e-15f);
  float ec = ftanh(nn) / fmaxf(nn, EPS);
  float nTE = ec * acc;
  float fs = ftanh(r * fA) / fnc;
  float xv = fs * fv;
  float x2 = fs * fs * f2;   // sqnorm(mob_scalar(f,r)) exactly
  float y2 = ec * ec * a2;   // sqnorm(nTE) exactly
  float xy = wred(xv * nTE);
  float num = (1.f + 2.f * xy + y2) * xv + (1.f - x2) * nTE;
  float dden = fmaxf(1.f + 2.f * xy + x2 * y2, EPS);
  return num / dden;
}

__global__ __launch_bounds__(256) void mode_kernel(ModeParams pm0, ModeParams pm1) {
  const int bid = blockIdx.x;
  const int mode = bid >= NROW;
  const ModeParams P = mode ? pm1 : pm0;
  const int n = bid - mode * NROW;
  const int tid = threadIdx.x;
  const int l = tid & 63;
  const int w = tid >> 6;

  __shared__ float Qs[FF][DH], Hs[FF][DH];
  __shared__ float Q2[FF], QN[FF], QA[FF];
  __shared__ float S2[FF], SN[FF], SA[FF];
  __shared__ float zb[2][DH];
  __shared__ float ub[DH];

  const float* f = P.f;
  float fv = f[n * DH + l];
  for (int i = w; i < FF; i += 4) {
    Hs[i][l] = f[P.Didx[n * FF + i] * DH + l];  // D tile (later becomes h_neigh)
    Qs[i][l] = f[P.Qidx[n * FF + i] * DH + l];
  }
  __syncthreads();

  // per-neighbor precompute: sqnorm, clipped norm, atanh(clipped norm)
  for (int i = w; i < FF; i += 4) {
    float qv = Qs[i][l];
    float s2 = wred(qv * qv);
    float dv = Hs[i][l];
    float t2 = wred(dv * dv);
    if (l == 0) {
      Q2[i] = s2;
      float ncq = clampn(sqrtf(s2 + 1e-15f));
      QN[i] = ncq;
      QA[i] = fatanh(ncq);
      S2[i] = t2;
      float ncd = clampn(sqrtf(t2 + 1e-15f));
      SN[i] = ncd;
      SA[i] = fatanh(ncd);
    }
  }
  __syncthreads();

  float f2 = wred(fv * fv);
  float fnc = clampn(sqrtf(f2 + 1e-15f));
  float fA = fatanh(fnc);
  float q1 = P.q1p[0], qsc = P.qp[0], qqsc = P.qqp[0];

  // ---- co-attention: wave w owns D slots i = w, w+4, ... (independent) ----
  for (int i = w; i < FF; i += 4) {
    float dl = Hs[i][l];
    float D2i = S2[i];
    float g[FF];
    float ssum = 0.f;
#pragma unroll
    for (int j = 0; j < FF; ++j) {
      float dif = dl - Qs[j][l];
      float d2 = wred(dif * dif);
      float den = fmaxf((1.f - D2i) * (1.f - Q2[j]), EPS);
      float arg = fmaxf(1.f + 2.f * d2 / den, 1.f + 1e-7f);
      g[j] = __expf(-facosh(arg));
      ssum += g[j];
    }
    float inv = 1.f / ssum;
    float acc = 0.f;
#pragma unroll
    for (int j = 0; j < FF; ++j) {
      float gg = g[j] * inv;
      float t = ftanh(gg * QA[j]);   // tanh(G * artanh(|Q|))
      float yf = t / QN[j];          // mob_scalar factor
      float ny = sqrtf(yf * yf * Q2[j] + 1e-15f);
      float nc = clampn(ny);
      float k = fatanh(nc) / nc * yf;  // log0 factor * mob_scalar factor
      acc = fmaf(k, Qs[j][l], acc);
    }
    // nh = exp0(acc)
    float a2 = wred(acc * acc);
    float nn = sqrtf(a2 + 1e-15f);
    float ec = ftanh(nn) / fmaxf(nn, EPS);
    float nh = ec * acc;
    // mob_scalar(D_i, q1)
    float fDc = ftanh(q1 * SA[i]) / SN[i];
    float xv = fDc * dl;
    // mob_add(xv, nh): x2/y2 are exact scalars
    float x2 = fDc * fDc * D2i;
    float y2 = ec * ec * a2;
    float xy = wred(xv * nh);
    float num = (1.f + 2.f * xy + y2) * xv + (1.f - x2) * nh;
    float dden = fmaxf(1.f + 2.f * xy + x2 * y2, EPS);
    float hv = num / dden;
    float h2 = wred(hv * hv);
    Hs[i][l] = hv;  // own row: no cross-wave hazard
    if (l == 0) {
      S2[i] = h2;
      float nc = clampn(sqrtf(h2 + 1e-15f));
      SN[i] = nc;
      SA[i] = fatanh(nc);
    }
  }
  __syncthreads();

  // ---- aggregates on waves 0 / 1 in parallel ----
  if (w == 0) {
    float e1 = aggregate_fn(Hs, S2, SN, SA, fv, f2, fnc, fA, qsc, l);
    float e1s = wred(e1 * e1);
    float n1 = clampn(sqrtf(e1s + 1e-15f));
    zb[0][l] = fatanh(n1) / n1 * e1;
  } else if (w == 1) {
    float e2 = aggregate_fn(Qs, Q2, QN, QA, fv, f2, fnc, fA, qqsc, l);
    float e2s = wred(e2 * e2);
    float n2 = clampn(sqrtf(e2s + 1e-15f));
    zb[1][l] = fatanh(n2) / n2 * e2;
  }
  __syncthreads();

  // ---- beta softmax + rst + u (wave 0) ----
  if (w == 0) {
    int p_ = l >> 5, c_ = l & 31;
    float mm = P.ab1[c_];
#pragma unroll
    for (int k = 0; k < DH; ++k) mm = fmaf(zb[p_][k], P.aw1[k * 32 + c_], mm);
    float tt = ftanh(mm);
    float sr = tt * P.aw2[c_];
#pragma unroll
    for (int m = 16; m >= 1; m >>= 1) sr += __shfl_xor(sr, m, 64);
    float s0 = __shfl(sr, 0, 64);
    float s1 = __shfl(sr, 32, 64);
    float bm = fmaxf(s0, s1);
    float b0 = __expf(s0 - bm), b1 = __expf(s1 - bm);
    float bi = 1.f / (b0 + b1);
    b0 *= bi;
    b1 *= bi;
    float rv = fmaf(b0, zb[0][l], b1 * zb[1][l]);
    float r2 = wred(rv * rv);
    float rn = sqrtf(r2 + 1e-15f);
    float rst = ftanh(rn) / fmaxf(rn, EPS) * rv;
    float rr = wred(rst * rst);
    float rc = clampn(sqrtf(rr + 1e-15f));
    ub[l] = fatanh(rc) / rc * rst;
  }
  __syncthreads();

  // ---- out = exp0(u @ wout + bout) (wave 0) ----
  if (w == 0) {
    float oo = P.bout[l];
#pragma unroll
    for (int k = 0; k < DH; ++k) oo = fmaf(ub[k], P.wout[k * DH + l], oo);
    float o2 = wred(oo * oo);
    float on = sqrtf(o2 + 1e-15f);
    P.out[n * DH + l] = ftanh(on) / fmaxf(on, EPS) * oo;
  }
}

extern "C" void kernel_launch(void* const* d_in, const int* in_sizes, int n_in,
                              void* d_out, int out_size, void* d_ws,
                              size_t ws_size, hipStream_t stream) {
  const int* x = (const int*)d_in[0];
  const int* idx_sim = (const int*)d_in[1];
  const int* idx_cor = (const int*)d_in[2];
  // per-mode params: 0 emb0, 1 emb1, 2 win, 3 bin, 4 q, 5 qq, 6 q1,
  //                  7 aw1, 8 ab1, 9 aw2, 10 wout, 11 bout
  const float* p[2][12];
  for (int m = 0; m < 2; ++m)
    for (int k = 0; k < 12; ++k) p[m][k] = (const float*)d_in[3 + m * 12 + k];

  float* fsim = (float*)d_ws;
  float* fcor = fsim + NROW * DH;
  float* out = (float*)d_out;

  FeatParams fps = {p[0][0], p[0][1], p[0][2], p[0][3], fsim};
  FeatParams fpc = {p[1][0], p[1][1], p[1][2], p[1][3], fcor};
  feat_kernel<<<2 * NROW, 64, 0, stream>>>(x, fps, fpc);

  // mode 'sim': D = f[idx_cor], Q = f[idx_sim]; mode 'cor': swapped
  ModeParams m0 = {fsim, idx_cor, idx_sim, p[0][6], p[0][4], p[0][5],
                   p[0][7], p[0][8], p[0][9], p[0][10], p[0][11], out};
  ModeParams m1 = {fcor, idx_sim, idx_cor, p[1][6], p[1][4], p[1][5],
                   p[1][7], p[1][8], p[1][9], p[1][10], p[1][11], out + NROW * DH};
  mode_kernel<<<2 * NROW, 256, 0, stream>>>(m0, m1);
}

// Round 3
// 79.373 us; speedup vs baseline: 8.1548x; 6.4453x over previous
//
#include <hip/hip_runtime.h>

#define EPS 1e-5f
#define ONE_M_EPS (1.0f - 1e-5f)
#define NROW 2048
#define FF 20
#define DH 64
#define PADW (DH + 4)        // 68: rows stay 16B-aligned, banks spread
#define NPAIR (FF * FF)      // 400
#define NPAIR2 (NPAIR + FF)  // + f.Q dots

__device__ __forceinline__ float wred(float v) {
#pragma unroll
  for (int m = 32; m >= 1; m >>= 1) v += __shfl_xor(v, m, 64);
  return v;
}

__device__ __forceinline__ float ftanh(float x) {
  float ax = fabsf(x);
  float e = __expf(-2.f * ax);
  float t = (1.f - e) / (1.f + e);
  return copysignf(t, x);
}

__device__ __forceinline__ float fatanh(float x) {  // x in [0, 1-EPS]
  return 0.5f * __logf((1.f + x) / (1.f - x));
}

__device__ __forceinline__ float facosh(float x) {  // x >= 1
  return __logf(x + sqrtf(fmaxf(x * x - 1.f, 0.f)));
}

__device__ __forceinline__ float clampn(float x) {
  return fminf(fmaxf(x, EPS), ONE_M_EPS);
}

struct FeatParams {
  const float *emb0, *emb1, *win, *bin;
  float* fout;
};

struct ModeParams {
  const float* f;
  const int *Didx, *Qidx;
  const float *q1p, *qp, *qqp, *aw1, *ab1, *aw2, *wout, *bout;
  float* out;
};

// f = exp0(concat(emb0[x0], emb1[x1]) @ win + bin); both modes in one grid
__global__ __launch_bounds__(64) void feat_kernel(const int* __restrict__ x,
                                                  FeatParams ps, FeatParams pc) {
  const int bid = blockIdx.x;
  const int mode = bid >= NROW;
  const FeatParams P = mode ? pc : ps;
  const int n = bid - mode * NROW;
  const int l = threadIdx.x;
  __shared__ float u[DH];
  int x0 = x[n * 2 + 0];
  int x1 = x[n * 2 + 1];
  u[l] = (l < 32) ? P.emb0[x0 * 32 + l] : P.emb1[x1 * 32 + (l - 32)];
  __syncthreads();
  float acc = P.bin[l];
#pragma unroll
  for (int k = 0; k < DH; ++k) acc = fmaf(u[k], P.win[k * DH + l], acc);
  float a2 = wred(acc * acc);
  float nn = sqrtf(a2 + 1e-15f);
  P.fout[n * DH + l] = ftanh(nn) / fmaxf(nn, EPS) * acc;
}

__global__ __launch_bounds__(256) void mode_kernel(ModeParams pm0, ModeParams pm1) {
  const int bid = blockIdx.x;
  const int mode = bid >= NROW;
  const ModeParams P = mode ? pm1 : pm0;
  const int n = bid - mode * NROW;
  const int tid = threadIdx.x;
  const int l = tid & 63;
  const int w = tid >> 6;

  __shared__ alignas(16) float Ds[FF][PADW];  // D rows; becomes h_neigh after P5
  __shared__ alignas(16) float Qs[FF][PADW];
  __shared__ alignas(16) float fs_[PADW];
  __shared__ float Gm[NPAIR];  // raw->g->coeff (single-owner overwrite)
  __shared__ float Fq[FF];     // f.Q dots
  __shared__ float inv_[FF];
  __shared__ float D2[FF], DN[FF], DA[FF];
  __shared__ float Q2[FF], QN[FF], QA[FF];
  __shared__ float A1[FF], A2v[FF], C1[FF], C2[FF];
  __shared__ float zb[2][DH];
  __shared__ float ub[DH];
  __shared__ float pb[4][DH];

  const float* f = P.f;
  float fv = f[n * DH + l];

  // ---- P0: gather tiles ----
  for (int i = w; i < FF; i += 4) {
    Ds[i][l] = f[P.Didx[n * FF + i] * DH + l];
    Qs[i][l] = f[P.Qidx[n * FF + i] * DH + l];
  }
  if (w == 0) fs_[l] = fv;
  float f2 = wred(fv * fv);  // per-wave uniform
  float fnc = clampn(sqrtf(f2 + 1e-15f));
  float fA = fatanh(fnc);
  float q1 = P.q1p[0], qsc = P.qp[0], qqsc = P.qqp[0];
  __syncthreads();

  // ---- P1: row norms (wred, rows w-strided) ----
  for (int r = w; r < 2 * FF; r += 4) {
    float v = (r < FF) ? Ds[r][l] : Qs[r - FF][l];
    float s2 = wred(v * v);
    if (l == 0) {
      float nc = clampn(sqrtf(s2 + 1e-15f));
      float at = fatanh(nc);
      if (r < FF) {
        D2[r] = s2; DN[r] = nc; DA[r] = at;
      } else {
        Q2[r - FF] = s2; QN[r - FF] = nc; QA[r - FF] = at;
      }
    }
  }
  __syncthreads();

  // ---- P2: per-thread pair dots + dist -> g ----
  for (int p = tid; p < NPAIR2; p += 256) {
    int i = p / FF;
    int j = p - i * FF;
    const float4* ap =
        (i < FF) ? (const float4*)(&Ds[i][0]) : (const float4*)(&fs_[0]);
    const float4* bp = (const float4*)(&Qs[j][0]);
    float dot = 0.f;
#pragma unroll
    for (int kk = 0; kk < DH / 4; ++kk) {
      float4 a = ap[kk];
      float4 b = bp[kk];
      dot = fmaf(a.x, b.x, dot);
      dot = fmaf(a.y, b.y, dot);
      dot = fmaf(a.z, b.z, dot);
      dot = fmaf(a.w, b.w, dot);
    }
    if (i < FF) {
      float d2 = D2[i] + Q2[j] - 2.f * dot;
      float den = fmaxf((1.f - D2[i]) * (1.f - Q2[j]), EPS);
      float arg = fmaxf(1.f + 2.f * d2 / den, 1.f + 1e-7f);
      Gm[p] = __expf(-facosh(arg));
    } else {
      Fq[j] = dot;
    }
  }
  __syncthreads();

  // ---- P3: softmax denominators (20 threads) ----
  if (tid < FF) {
    float s = 0.f;
#pragma unroll
    for (int j = 0; j < FF; ++j) s += Gm[tid * FF + j];
    inv_[tid] = 1.f / s;
  }
  __syncthreads();

  // ---- P4: per-pair coefficient chain (single-owner Gm overwrite) ----
  for (int p = tid; p < NPAIR; p += 256) {
    int i = p / FF;
    int j = p - i * FF;
    float gg = Gm[p] * inv_[i];
    float t = ftanh(gg * QA[j]);
    float yf = t / QN[j];
    float ny = sqrtf(yf * yf * Q2[j] + 1e-15f);
    float nc = clampn(ny);
    Gm[p] = fatanh(nc) / nc * yf;
  }
  __syncthreads();

  // ---- P5: per-slot weighted sum + exp0 + mob_add -> H ----
  for (int i = w; i < FF; i += 4) {
    float acc = 0.f;
#pragma unroll
    for (int j = 0; j < FF; ++j) acc = fmaf(Gm[i * FF + j], Qs[j][l], acc);
    float a2 = wred(acc * acc);
    float nn = sqrtf(a2 + 1e-15f);
    float ec = ftanh(nn) / fmaxf(nn, EPS);
    float nh = ec * acc;
    float fDc = ftanh(q1 * DA[i]) / DN[i];
    float dl = Ds[i][l];
    float xv = fDc * dl;
    float x2 = fDc * fDc * D2[i];
    float y2 = ec * ec * a2;
    float xy = wred(xv * nh);
    float al = 1.f + 2.f * xy + y2;
    float be = 1.f - x2;
    float rd = 1.f / fmaxf(1.f + 2.f * xy + x2 * y2, EPS);
    Ds[i][l] = (al * xv + be * nh) * rd;
    if (l == 0) {
      float h2 = (al * al * x2 + 2.f * al * be * xy + be * be * y2) * rd * rd;
      float nc = clampn(sqrtf(h2 + 1e-15f));
      D2[i] = h2; DN[i] = nc; DA[i] = fatanh(nc);
    }
  }
  __syncthreads();

  // ---- P6a: aggregate distances (e1 on wave0 threads, e2 on wave1 threads) --
  if (tid < FF) {
    const float4* ap = (const float4*)(&fs_[0]);
    const float4* bp = (const float4*)(&Ds[tid][0]);
    float dot = 0.f;
#pragma unroll
    for (int kk = 0; kk < DH / 4; ++kk) {
      float4 a = ap[kk];
      float4 b = bp[kk];
      dot = fmaf(a.x, b.x, dot);
      dot = fmaf(a.y, b.y, dot);
      dot = fmaf(a.z, b.z, dot);
      dot = fmaf(a.w, b.w, dot);
    }
    float d2 = f2 + D2[tid] - 2.f * dot;
    float den = fmaxf((1.f - f2) * (1.f - D2[tid]), EPS);
    float arg = fmaxf(1.f + 2.f * d2 / den, 1.f + 1e-7f);
    A1[tid] = __expf(-facosh(arg));
  } else if (tid >= 64 && tid < 64 + FF) {
    int j = tid - 64;
    float d2 = f2 + Q2[j] - 2.f * Fq[j];
    float den = fmaxf((1.f - f2) * (1.f - Q2[j]), EPS);
    float arg = fmaxf(1.f + 2.f * d2 / den, 1.f + 1e-7f);
    A2v[j] = __expf(-facosh(arg));
  }
  __syncthreads();

  // ---- P6b: aggregate coefficients ----
  if (tid < FF) {
    float s = 0.f;
#pragma unroll
    for (int j = 0; j < FF; ++j) s += A1[j];
    float gg = A1[tid] / s;
    float t = ftanh(gg * DA[tid]);
    float yf = t / DN[tid];
    float ny = sqrtf(yf * yf * D2[tid] + 1e-15f);
    float nc = clampn(ny);
    C1[tid] = fatanh(nc) / nc * yf;
  } else if (tid >= 64 && tid < 64 + FF) {
    int j = tid - 64;
    float s = 0.f;
#pragma unroll
    for (int jj = 0; jj < FF; ++jj) s += A2v[jj];
    float gg = A2v[j] / s;
    float t = ftanh(gg * QA[j]);
    float yf = t / QN[j];
    float ny = sqrtf(yf * yf * Q2[j] + 1e-15f);
    float nc = clampn(ny);
    C2[j] = fatanh(nc) / nc * yf;
  }
  __syncthreads();

  // ---- P6c: e1 (wave0) / e2 (wave1) weighted sums + mob_add + log0 -> zb ----
  if (w < 2) {
    const float* C = (w == 0) ? C1 : C2;
    float r = (w == 0) ? qsc : qqsc;
    float acc = 0.f;
    if (w == 0) {
#pragma unroll
      for (int j = 0; j < FF; ++j) acc = fmaf(C[j], Ds[j][l], acc);
    } else {
#pragma unroll
      for (int j = 0; j < FF; ++j) acc = fmaf(C[j], Qs[j][l], acc);
    }
    float a2 = wred(acc * acc);
    float nn = sqrtf(a2 + 1e-15f);
    float ec = ftanh(nn) / fmaxf(nn, EPS);
    float nTE = ec * acc;
    float fsc = ftanh(r * fA) / fnc;
    float xv = fsc * fv;
    float x2 = fsc * fsc * f2;
    float y2 = ec * ec * a2;
    float xy = wred(xv * nTE);
    float al = 1.f + 2.f * xy + y2;
    float be = 1.f - x2;
    float rd = 1.f / fmaxf(1.f + 2.f * xy + x2 * y2, EPS);
    float ev = (al * xv + be * nTE) * rd;
    float es = (al * al * x2 + 2.f * al * be * xy + be * be * y2) * rd * rd;
    float n1 = clampn(sqrtf(es + 1e-15f));
    zb[w][l] = fatanh(n1) / n1 * ev;
  }
  __syncthreads();

  // ---- P7: beta softmax + rst + u (wave0) ----
  if (w == 0) {
    int p_ = l >> 5, c_ = l & 31;
    float mm = P.ab1[c_];
#pragma unroll
    for (int k = 0; k < DH; ++k) mm = fmaf(zb[p_][k], P.aw1[k * 32 + c_], mm);
    float tt = ftanh(mm);
    float sr = tt * P.aw2[c_];
#pragma unroll
    for (int m = 16; m >= 1; m >>= 1) sr += __shfl_xor(sr, m, 64);
    float s0 = __shfl(sr, 0, 64);
    float s1 = __shfl(sr, 32, 64);
    float bm = fmaxf(s0, s1);
    float b0 = __expf(s0 - bm), b1 = __expf(s1 - bm);
    float bi = 1.f / (b0 + b1);
    b0 *= bi;
    b1 *= bi;
    float rv = fmaf(b0, zb[0][l], b1 * zb[1][l]);
    float r2 = wred(rv * rv);
    float rn = sqrtf(r2 + 1e-15f);
    float sc = ftanh(rn) / fmaxf(rn, EPS);
    float rst = sc * rv;
    float rr = sc * sc * r2;
    float rc = clampn(sqrtf(rr + 1e-15f));
    ub[l] = fatanh(rc) / rc * rst;
  }
  __syncthreads();

  // ---- P8: out = exp0(u @ wout + bout), k-split over 4 waves ----
  {
    float oo = 0.f;
#pragma unroll
    for (int k = 0; k < DH / 4; ++k) {
      int kk = w * (DH / 4) + k;
      oo = fmaf(ub[kk], P.wout[kk * DH + l], oo);
    }
    pb[w][l] = oo;
  }
  __syncthreads();
  if (w == 0) {
    float oo = P.bout[l] + ((pb[0][l] + pb[1][l]) + (pb[2][l] + pb[3][l]));
    float o2 = wred(oo * oo);
    float on = sqrtf(o2 + 1e-15f);
    P.out[n * DH + l] = ftanh(on) / fmaxf(on, EPS) * oo;
  }
}

extern "C" void kernel_launch(void* const* d_in, const int* in_sizes, int n_in,
                              void* d_out, int out_size, void* d_ws,
                              size_t ws_size, hipStream_t stream) {
  const int* x = (const int*)d_in[0];
  const int* idx_sim = (const int*)d_in[1];
  const int* idx_cor = (const int*)d_in[2];
  const float* p[2][12];
  for (int m = 0; m < 2; ++m)
    for (int k = 0; k < 12; ++k) p[m][k] = (const float*)d_in[3 + m * 12 + k];

  float* fsim = (float*)d_ws;
  float* fcor = fsim + NROW * DH;
  float* out = (float*)d_out;

  FeatParams fps = {p[0][0], p[0][1], p[0][2], p[0][3], fsim};
  FeatParams fpc = {p[1][0], p[1][1], p[1][2], p[1][3], fcor};
  feat_kernel<<<2 * NROW, 64, 0, stream>>>(x, fps, fpc);

  // mode 'sim': D = f[idx_cor], Q = f[idx_sim]; mode 'cor': swapped
  ModeParams m0 = {fsim, idx_cor, idx_sim, p[0][6], p[0][4], p[0][5],
                   p[0][7], p[0][8], p[0][9], p[0][10], p[0][11], out};
  ModeParams m1 = {fcor, idx_sim, idx_cor, p[1][6], p[1][4], p[1][5],
                   p[1][7], p[1][8], p[1][9], p[1][10], p[1][11], out + NROW * DH};
  mode_kernel<<<2 * NROW, 256, 0, stream>>>(m0, m1);
}

// Round 4
// 59.468 us; speedup vs baseline: 10.8844x; 1.3347x over previous
//
#include <hip/hip_runtime.h>

#define EPS 1e-5f
#define ONE_M_EPS (1.0f - 1e-5f)
#define NROW 2048
#define FF 20
#define DH 64
#define PADW (DH + 4)        // 68: rows stay 16B-aligned, banks spread
#define NPAIR (FF * FF)      // 400
#define NPAIR2 (NPAIR + FF)  // + f.Q dots

__device__ __forceinline__ float frcp(float x) { return __builtin_amdgcn_rcpf(x); }
__device__ __forceinline__ float fsq(float x) { return __builtin_amdgcn_sqrtf(x); }

__device__ __forceinline__ float wred(float v) {
#pragma unroll
  for (int m = 32; m >= 1; m >>= 1) v += __shfl_xor(v, m, 64);
  return v;
}

__device__ __forceinline__ float ftanh(float x) {
  float ax = fabsf(x);
  float e = __expf(-2.f * ax);
  float t = (1.f - e) * frcp(1.f + e);
  return copysignf(t, x);
}

__device__ __forceinline__ float fatanh(float x) {  // x in [0, 1-EPS]
  return 0.5f * __logf((1.f + x) * frcp(1.f - x));
}

__device__ __forceinline__ float facosh(float x) {  // x >= 1
  return __logf(x + fsq(fmaxf(x * x - 1.f, 0.f)));
}

__device__ __forceinline__ float clampn(float x) {
  return fminf(fmaxf(x, EPS), ONE_M_EPS);
}

struct FeatParams {
  const float *emb0, *emb1, *win, *bin;
  float* fout;
};

struct ModeParams {
  const float* f;
  const int *Didx, *Qidx;
  const float *q1p, *qp, *qqp, *aw1, *ab1, *aw2, *wout, *bout;
  float* out;
};

// f = exp0(concat(emb0[x0], emb1[x1]) @ win + bin); both modes in one grid
__global__ __launch_bounds__(64) void feat_kernel(const int* __restrict__ x,
                                                  FeatParams ps, FeatParams pc) {
  const int bid = blockIdx.x;
  const int mode = bid >= NROW;
  const FeatParams P = mode ? pc : ps;
  const int n = bid - mode * NROW;
  const int l = threadIdx.x;
  __shared__ float u[DH];
  int x0 = x[n * 2 + 0];
  int x1 = x[n * 2 + 1];
  u[l] = (l < 32) ? P.emb0[x0 * 32 + l] : P.emb1[x1 * 32 + (l - 32)];
  __syncthreads();
  float acc = P.bin[l];
#pragma unroll
  for (int k = 0; k < DH; ++k) acc = fmaf(u[k], P.win[k * DH + l], acc);
  float a2 = wred(acc * acc);
  float nn = fsq(a2 + 1e-15f);
  P.fout[n * DH + l] = ftanh(nn) * frcp(fmaxf(nn, EPS)) * acc;
}

__global__ __launch_bounds__(256) void mode_kernel(ModeParams pm0, ModeParams pm1) {
  const int bid = blockIdx.x;
  const int mode = bid >= NROW;
  const ModeParams P = mode ? pm1 : pm0;
  const int n = bid - mode * NROW;
  const int tid = threadIdx.x;
  const int l = tid & 63;
  const int w = tid >> 6;

  __shared__ alignas(16) float Ds[FF][PADW];  // D rows; becomes h_neigh after P5
  __shared__ alignas(16) float Qs[FF][PADW];
  __shared__ alignas(16) float fs_[PADW];
  __shared__ float Gm[NPAIR];  // raw->g->coeff (single-owner overwrite)
  __shared__ float Fq[FF];     // f.Q dots
  __shared__ float inv_[FF];
  __shared__ float D2[FF], DN[FF], DA[FF];
  __shared__ float Q2[FF], QN[FF], QA[FF];
  __shared__ float A1[FF], A2v[FF], C1[FF], C2[FF];
  __shared__ float zb[2][DH];
  __shared__ float ub[DH];
  __shared__ float pb[4][DH];

  const float* f = P.f;
  float fv = f[n * DH + l];

  // ---- P0: gather tiles ----
  for (int i = w; i < FF; i += 4) {
    Ds[i][l] = f[P.Didx[n * FF + i] * DH + l];
    Qs[i][l] = f[P.Qidx[n * FF + i] * DH + l];
  }
  if (w == 0) fs_[l] = fv;
  float f2 = wred(fv * fv);  // per-wave uniform
  float fnc = clampn(fsq(f2 + 1e-15f));
  float fA = fatanh(fnc);
  float q1 = P.q1p[0], qsc = P.qp[0], qqsc = P.qqp[0];
  __syncthreads();

  // ---- P1: row norms as per-thread self-dots (wave0: D, wave1: Q) ----
  if (w < 2 && l < FF) {
    const float4* rp =
        (w == 0) ? (const float4*)(&Ds[l][0]) : (const float4*)(&Qs[l][0]);
    float dot = 0.f;
#pragma unroll
    for (int kk = 0; kk < DH / 4; ++kk) {
      float4 a = rp[kk];
      dot = fmaf(a.x, a.x, dot);
      dot = fmaf(a.y, a.y, dot);
      dot = fmaf(a.z, a.z, dot);
      dot = fmaf(a.w, a.w, dot);
    }
    float nc = clampn(fsq(dot + 1e-15f));
    float at = fatanh(nc);
    if (w == 0) {
      D2[l] = dot; DN[l] = nc; DA[l] = at;
    } else {
      Q2[l] = dot; QN[l] = nc; QA[l] = at;
    }
  }
  __syncthreads();

  // cache Q columns in registers (lane l = column l)
  float qreg[FF];
#pragma unroll
  for (int j = 0; j < FF; ++j) qreg[j] = Qs[j][l];

  // ---- P2: per-thread pair dots + dist -> g ----
  for (int p = tid; p < NPAIR2; p += 256) {
    int i = p / FF;
    int j = p - i * FF;
    const float4* ap =
        (i < FF) ? (const float4*)(&Ds[i][0]) : (const float4*)(&fs_[0]);
    const float4* bp = (const float4*)(&Qs[j][0]);
    float dot = 0.f;
#pragma unroll
    for (int kk = 0; kk < DH / 4; ++kk) {
      float4 a = ap[kk];
      float4 b = bp[kk];
      dot = fmaf(a.x, b.x, dot);
      dot = fmaf(a.y, b.y, dot);
      dot = fmaf(a.z, b.z, dot);
      dot = fmaf(a.w, b.w, dot);
    }
    if (i < FF) {
      float d2 = D2[i] + Q2[j] - 2.f * dot;
      float den = fmaxf((1.f - D2[i]) * (1.f - Q2[j]), EPS);
      float arg = fmaxf(1.f + 2.f * d2 * frcp(den), 1.f + 1e-7f);
      Gm[p] = __expf(-facosh(arg));
    } else {
      Fq[j] = dot;
    }
  }
  __syncthreads();

  // ---- P3: softmax denominators (20 threads) ----
  if (tid < FF) {
    float s = 0.f;
#pragma unroll
    for (int j = 0; j < FF; ++j) s += Gm[tid * FF + j];
    inv_[tid] = frcp(s);
  }
  __syncthreads();

  // ---- P4: per-pair coefficient chain (single-owner Gm overwrite) ----
  for (int p = tid; p < NPAIR; p += 256) {
    int i = p / FF;
    int j = p - i * FF;
    float gg = Gm[p] * inv_[i];
    float t = ftanh(gg * QA[j]);
    float yf = t * frcp(QN[j]);
    float ny = fsq(yf * yf * Q2[j] + 1e-15f);
    float nc = clampn(ny);
    Gm[p] = fatanh(nc) * frcp(nc) * yf;
  }
  __syncthreads();

  // ---- P5: per-slot weighted sum + exp0 + mob_add -> H ----
  for (int i = w; i < FF; i += 4) {
    float acc = 0.f;
#pragma unroll
    for (int j = 0; j < FF; ++j) acc = fmaf(Gm[i * FF + j], qreg[j], acc);
    float a2 = wred(acc * acc);
    float nn = fsq(a2 + 1e-15f);
    float ec = ftanh(nn) * frcp(fmaxf(nn, EPS));
    float nh = ec * acc;
    float fDc = ftanh(q1 * DA[i]) * frcp(DN[i]);
    float dl = Ds[i][l];
    float xv = fDc * dl;
    float x2 = fDc * fDc * D2[i];
    float y2 = ec * ec * a2;
    float xy = wred(xv * nh);
    float al = 1.f + 2.f * xy + y2;
    float be = 1.f - x2;
    float rd = frcp(fmaxf(1.f + 2.f * xy + x2 * y2, EPS));
    Ds[i][l] = (al * xv + be * nh) * rd;
    float h2 = (al * al * x2 + 2.f * al * be * xy + be * be * y2) * rd * rd;
    if (l == 0) {
      float nc = clampn(fsq(h2 + 1e-15f));
      D2[i] = h2; DN[i] = nc; DA[i] = fatanh(nc);
    }
  }
  __syncthreads();

  // ---- P6a: aggregate distances (e1 on threads 0-19, e2 on threads 64-83) --
  if (tid < FF) {
    const float4* ap = (const float4*)(&fs_[0]);
    const float4* bp = (const float4*)(&Ds[tid][0]);
    float dot = 0.f;
#pragma unroll
    for (int kk = 0; kk < DH / 4; ++kk) {
      float4 a = ap[kk];
      float4 b = bp[kk];
      dot = fmaf(a.x, b.x, dot);
      dot = fmaf(a.y, b.y, dot);
      dot = fmaf(a.z, b.z, dot);
      dot = fmaf(a.w, b.w, dot);
    }
    float d2 = f2 + D2[tid] - 2.f * dot;
    float den = fmaxf((1.f - f2) * (1.f - D2[tid]), EPS);
    float arg = fmaxf(1.f + 2.f * d2 * frcp(den), 1.f + 1e-7f);
    A1[tid] = __expf(-facosh(arg));
  } else if (tid >= 64 && tid < 64 + FF) {
    int j = tid - 64;
    float d2 = f2 + Q2[j] - 2.f * Fq[j];
    float den = fmaxf((1.f - f2) * (1.f - Q2[j]), EPS);
    float arg = fmaxf(1.f + 2.f * d2 * frcp(den), 1.f + 1e-7f);
    A2v[j] = __expf(-facosh(arg));
  }
  __syncthreads();

  // ---- P6b: aggregate coefficients ----
  if (tid < FF) {
    float s = 0.f;
#pragma unroll
    for (int j = 0; j < FF; ++j) s += A1[j];
    float gg = A1[tid] * frcp(s);
    float t = ftanh(gg * DA[tid]);
    float yf = t * frcp(DN[tid]);
    float ny = fsq(yf * yf * D2[tid] + 1e-15f);
    float nc = clampn(ny);
    C1[tid] = fatanh(nc) * frcp(nc) * yf;
  } else if (tid >= 64 && tid < 64 + FF) {
    int j = tid - 64;
    float s = 0.f;
#pragma unroll
    for (int jj = 0; jj < FF; ++jj) s += A2v[jj];
    float gg = A2v[j] * frcp(s);
    float t = ftanh(gg * QA[j]);
    float yf = t * frcp(QN[j]);
    float ny = fsq(yf * yf * Q2[j] + 1e-15f);
    float nc = clampn(ny);
    C2[j] = fatanh(nc) * frcp(nc) * yf;
  }
  __syncthreads();

  // ---- P6c: e1 (wave0) / e2 (wave1) weighted sums + mob_add + log0 -> zb ----
  if (w < 2) {
    const float* C = (w == 0) ? C1 : C2;
    float r = (w == 0) ? qsc : qqsc;
    float acc = 0.f;
    if (w == 0) {
#pragma unroll
      for (int j = 0; j < FF; ++j) acc = fmaf(C[j], Ds[j][l], acc);
    } else {
#pragma unroll
      for (int j = 0; j < FF; ++j) acc = fmaf(C[j], qreg[j], acc);
    }
    float a2 = wred(acc * acc);
    float nn = fsq(a2 + 1e-15f);
    float ec = ftanh(nn) * frcp(fmaxf(nn, EPS));
    float nTE = ec * acc;
    float fsc = ftanh(r * fA) * frcp(fnc);
    float xv = fsc * fv;
    float x2 = fsc * fsc * f2;
    float y2 = ec * ec * a2;
    float xy = wred(xv * nTE);
    float al = 1.f + 2.f * xy + y2;
    float be = 1.f - x2;
    float rd = frcp(fmaxf(1.f + 2.f * xy + x2 * y2, EPS));
    float ev = (al * xv + be * nTE) * rd;
    float es = (al * al * x2 + 2.f * al * be * xy + be * be * y2) * rd * rd;
    float n1 = clampn(fsq(es + 1e-15f));
    zb[w][l] = fatanh(n1) * frcp(n1) * ev;
  }
  __syncthreads();

  // ---- P7: beta softmax + rst + u (wave0) ----
  if (w == 0) {
    int p_ = l >> 5, c_ = l & 31;
    float mm = P.ab1[c_];
#pragma unroll
    for (int k = 0; k < DH; ++k) mm = fmaf(zb[p_][k], P.aw1[k * 32 + c_], mm);
    float tt = ftanh(mm);
    float sr = tt * P.aw2[c_];
#pragma unroll
    for (int m = 16; m >= 1; m >>= 1) sr += __shfl_xor(sr, m, 64);
    float s0 = __shfl(sr, 0, 64);
    float s1 = __shfl(sr, 32, 64);
    float bm = fmaxf(s0, s1);
    float b0 = __expf(s0 - bm), b1 = __expf(s1 - bm);
    float bi = frcp(b0 + b1);
    b0 *= bi;
    b1 *= bi;
    float rv = fmaf(b0, zb[0][l], b1 * zb[1][l]);
    float r2 = wred(rv * rv);
    float rn = fsq(r2 + 1e-15f);
    float sc = ftanh(rn) * frcp(fmaxf(rn, EPS));
    float rst = sc * rv;
    float rr = sc * sc * r2;
    float rc = clampn(fsq(rr + 1e-15f));
    ub[l] = fatanh(rc) * frcp(rc) * rst;
  }
  __syncthreads();

  // ---- P8: out = exp0(u @ wout + bout), k-split over 4 waves ----
  {
    float oo = 0.f;
#pragma unroll
    for (int k = 0; k < DH / 4; ++k) {
      int kk = w * (DH / 4) + k;
      oo = fmaf(ub[kk], P.wout[kk * DH + l], oo);
    }
    pb[w][l] = oo;
  }
  __syncthreads();
  if (w == 0) {
    float oo = P.bout[l] + ((pb[0][l] + pb[1][l]) + (pb[2][l] + pb[3][l]));
    float o2 = wred(oo * oo);
    float on = fsq(o2 + 1e-15f);
    P.out[n * DH + l] = ftanh(on) * frcp(fmaxf(on, EPS)) * oo;
  }
}

extern "C" void kernel_launch(void* const* d_in, const int* in_sizes, int n_in,
                              void* d_out, int out_size, void* d_ws,
                              size_t ws_size, hipStream_t stream) {
  const int* x = (const int*)d_in[0];
  const int* idx_sim = (const int*)d_in[1];
  const int* idx_cor = (const int*)d_in[2];
  const float* p[2][12];
  for (int m = 0; m < 2; ++m)
    for (int k = 0; k < 12; ++k) p[m][k] = (const float*)d_in[3 + m * 12 + k];

  float* fsim = (float*)d_ws;
  float* fcor = fsim + NROW * DH;
  float* out = (float*)d_out;

  FeatParams fps = {p[0][0], p[0][1], p[0][2], p[0][3], fsim};
  FeatParams fpc = {p[1][0], p[1][1], p[1][2], p[1][3], fcor};
  feat_kernel<<<2 * NROW, 64, 0, stream>>>(x, fps, fpc);

  // mode 'sim': D = f[idx_cor], Q = f[idx_sim]; mode 'cor': swapped
  ModeParams m0 = {fsim, idx_cor, idx_sim, p[0][6], p[0][4], p[0][5],
                   p[0][7], p[0][8], p[0][9], p[0][10], p[0][11], out};
  ModeParams m1 = {fcor, idx_sim, idx_cor, p[1][6], p[1][4], p[1][5],
                   p[1][7], p[1][8], p[1][9], p[1][10], p[1][11], out + NROW * DH};
  mode_kernel<<<2 * NROW, 256, 0, stream>>>(m0, m1);
}